// Round 4
// baseline (224.612 us; speedup 1.0000x reference)
//
#include <hip/hip_runtime.h>
#include <math.h>

// Shapes fixed by setup_inputs(): x[8, 4096, 1024] fp32, output same.
#define Bb 8
#define Tt 4096
#define Dd 1024
#define EPSf 1e-5f
#define EPSVARf 1e-4f
#define NSEG 256          // segments per (b) along T; 1 segment per wave
#define NSEG_LOG2 8
#define SEGT (Tt / NSEG)  // 16 rows per segment
#define GRID_BLOCKS 512   // 2 blocks/CU x 256 CUs -> all co-resident (barrier-safe)
#define NBLK 512u

typedef float v4f __attribute__((ext_vector_type(4)));

// tanh(y) = 1 - 2/(exp(2y)+1); saturates correctly for |y| large
__device__ __forceinline__ float fast_tanh(float y) {
    float e = __expf(2.0f * y);
    return fmaf(-2.0f, __builtin_amdgcn_rcpf(e + 1.0f), 1.0f);
}

__device__ __forceinline__ float softplus_f(float v) { return log1pf(expf(v)); }

// Manual grid barrier (cooperative launch fails under the harness's graph
// capture -> round-3 all-zero output). Safety: __launch_bounds__(256,2) +
// LDS ~15KB guarantee >=2 blocks/CU, grid = 2*256 -> all blocks co-resident.
// __threadfence() at agent scope performs the L2 writeback/invalidate needed
// for cross-XCD visibility (per-XCD L2s are not coherent otherwise).
__device__ __forceinline__ void grid_barrier(unsigned* bar) {
    __syncthreads();                 // drains block's stores to its L2
    if (threadIdx.x == 0) {
        __threadfence();             // release: write back to device scope
        __hip_atomic_fetch_add(bar, 1u, __ATOMIC_RELEASE, __HIP_MEMORY_SCOPE_AGENT);
        while (__hip_atomic_load(bar, __ATOMIC_RELAXED, __HIP_MEMORY_SCOPE_AGENT) < NBLK)
            __builtin_amdgcn_s_sleep(1);
        __threadfence();             // acquire: invalidate stale lines
    }
    __syncthreads();
}

// ---------------- single fused kernel ----------------------------------------
// Phase A: prep (per-d consts -> LDS, block reduce burst/||ema_out||) +
//          per-row gate constants (A,B) -> LDS + segment totals -> segp.
// barrier
// Phase B: in-place exclusive scan of segp over segments (all 512 blocks).
// barrier
// Phase C: causal z3 + gelu + gate (A,B from LDS), nontemporal out stores.
__global__ __launch_bounds__(256, 2) void fused_all_kernel(
    const float* __restrict__ x,
    const float* __restrict__ ema_mean, const float* __restrict__ ema_sq,
    const float* __restrict__ ema_out,
    const float* __restrict__ var_fast, const float* __restrict__ var_slow,
    const float* __restrict__ p_log_tau, const float* __restrict__ p_log_sig1,
    const float* __restrict__ p_log_sig2, const float* __restrict__ p_log_sig3,
    const float* __restrict__ p_log_w, const float* __restrict__ p_log_a1,
    const float* __restrict__ p_log_a2, const float* __restrict__ p_log_a3,
    unsigned* __restrict__ bar, float* __restrict__ segp,
    float* __restrict__ out)
{
    __shared__ float s_iv[Dd], s_cc[Dd], s_eo[Dd];
    __shared__ float s_red[8];
    __shared__ float s_ab[4][SEGT * 2];      // per-wave row gates (A,B)
    __shared__ float lx[16][16], ls[16][16]; // scan partials

    int tid = threadIdx.x;
    int lane = tid & 63;
    int wv = tid >> 6;
    int d0 = lane * 4;

    // ---- prep: per-d constants into LDS + block reductions ----
    float brs = 0.f, ses = 0.f;
    {
        int dd = tid * 4;
        float4 m4 = *(const float4*)(ema_mean + dd);
        float4 q4 = *(const float4*)(ema_sq + dd);
        float4 e4 = *(const float4*)(ema_out + dd);
        float4 vf = *(const float4*)(var_fast + dd);
        float4 vs = *(const float4*)(var_slow + dd);
        float4 ivv, ccv;
#define PREP(C) { \
        float m = m4.C; \
        float vg = fmaxf(q4.C - m * m, EPSVARf); \
        float ivd = 1.0f / (sqrtf(vg) + EPSf); \
        ivv.C = ivd; ccv.C = m * ivd; \
        brs += fminf(vf.C / fmaxf(vs.C, EPSVARf), 10.0f); \
        ses = fmaf(e4.C, e4.C, ses); }
        PREP(x) PREP(y) PREP(z) PREP(w)
#undef PREP
        *(float4*)(s_iv + dd) = ivv;
        *(float4*)(s_cc + dd) = ccv;
        *(float4*)(s_eo + dd) = e4;
    }
    #pragma unroll
    for (int off = 32; off > 0; off >>= 1) {
        brs += __shfl_xor(brs, off);
        ses += __shfl_xor(ses, off);
    }
    if (lane == 0) { s_red[wv] = brs; s_red[4 + wv] = ses; }
    __syncthreads();
    brs = s_red[0] + s_red[1] + s_red[2] + s_red[3];
    ses = s_red[4] + s_red[5] + s_red[6] + s_red[7];

    // scalar params (redundant per thread; broadcast loads)
    float tau  = expf(p_log_tau[0]);
    float k1   = softplus_f(p_log_sig1[0]) * (1.0f / (float)Dd);
    float sig2 = softplus_f(p_log_sig2[0]);
    float k3   = softplus_f(p_log_sig3[0]) * (1.0f / (float)Dd);
    float w    = softplus_f(p_log_w[0]);
    float a1   = softplus_f(p_log_a1[0]);
    float a2   = softplus_f(p_log_a2[0]);
    float a3   = softplus_f(p_log_a3[0]);
    float burst = fmaxf(brs * (1.0f / (float)Dd) - 1.0f, 0.0f);
    float surp2 = tanhf(sig2 * burst);
    float s2p   = expf(a2 * logf(fmaxf(surp2, 1e-7f)));
    float inv_en = 1.0f / fmaxf(sqrtf(ses), 1e-12f);

    int gw = blockIdx.x * 4 + wv;            // 0..2047, one segment per wave
    int b = gw >> NSEG_LOG2, seg = gw & (NSEG - 1);
    int t0 = seg * SEGT;

    // ================= Phase A: gates + segment totals =================
    {
        const float* xr = x + ((size_t)b * Tt + t0) * Dd + d0;

        float4 rsx[4] = {{0,0,0,0},{0,0,0,0},{0,0,0,0},{0,0,0,0}};
        float4 rss[4] = {{0,0,0,0},{0,0,0,0},{0,0,0,0},{0,0,0,0}};

        float4 xv[4];
        #pragma unroll
        for (int j = 0; j < 4; ++j) xv[j] = *(const float4*)(xr + 256 * j);

        #pragma unroll 1
        for (int i = 0; i < SEGT; ++i) {
            float4 xn[4];
            if (i + 1 < SEGT) {
                #pragma unroll
                for (int j = 0; j < 4; ++j) xn[j] = *(const float4*)(xr + Dd + 256 * j);
            }
            float p1 = 0.f, pg2 = 0.f, pge = 0.f;

#define COMP(J, C) { \
            float xvv = xv[J].C; \
            p1 += fabsf(fmaf(xvv, ivj.C, -ccj.C)); \
            float xx = xvv * xvv; \
            float u2 = xvv * fmaf(0.07135481628f, xx, 1.59576912161f); \
            float e  = __expf(u2); \
            float th = fmaf(-2.0f, __builtin_amdgcn_rcpf(e + 1.0f), 1.0f); \
            float hx = 0.5f * xvv; \
            float gg = fmaf(hx, th, hx); \
            pg2 = fmaf(gg, gg, pg2); \
            pge = fmaf(gg, eoj.C, pge); \
            rsx[J].C += xvv; \
            rss[J].C = fmaf(xvv, xvv, rss[J].C); \
        }
            #pragma unroll
            for (int j = 0; j < 4; ++j) {
                float4 ivj = *(const float4*)(s_iv + d0 + 256 * j);
                float4 ccj = *(const float4*)(s_cc + d0 + 256 * j);
                float4 eoj = *(const float4*)(s_eo + d0 + 256 * j);
                COMP(j, x) COMP(j, y) COMP(j, z) COMP(j, w)
            }
#undef COMP

            #pragma unroll
            for (int off = 32; off > 0; off >>= 1) {
                p1  += __shfl_xor(p1,  off);
                pg2 += __shfl_xor(pg2, off);
                pge += __shfl_xor(pge, off);
            }
            float surp1 = fast_tanh(k1 * p1);
            float s1p = __expf(a1 * __logf(fmaxf(surp1, 1e-7f)));
            float rg = __builtin_amdgcn_rsqf(fmaxf(pg2, 1e-24f));
            float cs = fminf(fmaxf(pge * rg * inv_en, -1.0f), 1.0f);
            float A = __expf(-tau * cs);
            float Bv = A * w * s1p * s2p;
            if (lane == 0) { s_ab[wv][2 * i] = A; s_ab[wv][2 * i + 1] = Bv; }

            #pragma unroll
            for (int j = 0; j < 4; ++j) xv[j] = xn[j];
            xr += Dd;
        }

        // interleaved segment totals: (sx,ss) pairs, 32 B contiguous per lane
        float* sp = segp + ((size_t)(b * NSEG + seg) * Dd + d0) * 2;
        #pragma unroll
        for (int j = 0; j < 4; ++j) {
            float4 lo, hi;
            lo.x = rsx[j].x; lo.y = rss[j].x; lo.z = rsx[j].y; lo.w = rss[j].y;
            hi.x = rsx[j].z; hi.y = rss[j].z; hi.z = rsx[j].w; hi.w = rss[j].w;
            *(float4*)(sp + 512 * j) = lo;
            *(float4*)(sp + 512 * j + 4) = hi;
        }
    }

    grid_barrier(bar + 0);

    // ================= Phase B: exclusive scan over segments =================
    {
        constexpr int K = 16;
        constexpr int COLS = 16;
        constexpr int CH = NSEG / K;       // 16
        int col = tid & (COLS - 1);
        int q = tid >> 4;                  // 0..15
        int gcol = blockIdx.x * COLS + col;   // 0 .. B*D-1 (8192)
        int bb = gcol >> 10, d = gcol & 1023;
        float2* p = (float2*)segp + ((size_t)bb * NSEG + (size_t)q * CH) * Dd + d;

        float ax = 0.f, as = 0.f;
        #pragma unroll 4
        for (int s = 0; s < CH; ++s) {
            float2 v = p[(size_t)s * Dd];
            ax += v.x; as += v.y;
        }
        lx[q][col] = ax; ls[q][col] = as;
        __syncthreads();
        float rx = 0.f, rs = 0.f;
        for (int rr = 0; rr < q; ++rr) { rx += lx[rr][col]; rs += ls[rr][col]; }

        #pragma unroll 4
        for (int s = 0; s < CH; ++s) {
            size_t o = (size_t)s * Dd;
            float2 v = p[o];
            float2 e; e.x = rx; e.y = rs;
            p[o] = e;
            rx += v.x; rs += v.y;
        }
    }

    grid_barrier(bar + 1);

    // ================= Phase C: z3 + gelu + gate + store =================
    {
        const float* xr = x + ((size_t)b * Tt + t0) * Dd + d0;
        float* orow = out + ((size_t)b * Tt + t0) * Dd + d0;

        float4 xv[4];
        #pragma unroll
        for (int j = 0; j < 4; ++j) xv[j] = *(const float4*)(xr + 256 * j);

        float4 rsx[4], rss[4];
        const float* sp = segp + ((size_t)(b * NSEG + seg) * Dd + d0) * 2;
        #pragma unroll
        for (int j = 0; j < 4; ++j) {
            float4 lo = *(const float4*)(sp + 512 * j);
            float4 hi = *(const float4*)(sp + 512 * j + 4);
            rsx[j].x = lo.x; rss[j].x = lo.y; rsx[j].y = lo.z; rss[j].y = lo.w;
            rsx[j].z = hi.x; rss[j].z = hi.y; rsx[j].w = hi.z; rss[j].w = hi.w;
        }

        #pragma unroll 1
        for (int i = 0; i < SEGT; ++i) {
            int t = t0 + i;
            float4 xn[4];
            if (i + 1 < SEGT) {
                #pragma unroll
                for (int j = 0; j < 4; ++j) xn[j] = *(const float4*)(xr + Dd + 256 * j);
            }
            float Ag = s_ab[wv][2 * i];
            float Bg = s_ab[wv][2 * i + 1];

            float p3 = 0.f;
            float4 g[4];
            float invt = (t > 0) ? __builtin_amdgcn_rcpf((float)t) : 0.0f;

#define COMP(J, C) { \
            float xvv = xv[J].C; \
            float mu = rsx[J].C * invt; \
            float vr = fmaxf(fmaf(-mu, mu, rss[J].C * invt), EPSVARf); \
            float rq = __builtin_amdgcn_rsqf(vr); \
            float ri = rq * fmaf(-EPSf, rq, 1.0f); \
            p3 += fabsf((xvv - mu) * ri); \
            float xx = xvv * xvv; \
            float u2 = xvv * fmaf(0.07135481628f, xx, 1.59576912161f); \
            float e  = __expf(u2); \
            float th = fmaf(-2.0f, __builtin_amdgcn_rcpf(e + 1.0f), 1.0f); \
            float hx = 0.5f * xvv; \
            g[J].C = fmaf(hx, th, hx); \
            rsx[J].C += xvv; \
            rss[J].C = fmaf(xvv, xvv, rss[J].C); \
        }
            #pragma unroll
            for (int j = 0; j < 4; ++j) { COMP(j, x) COMP(j, y) COMP(j, z) COMP(j, w) }
#undef COMP
            if (t == 0) p3 = 0.f;   // reference forces z3[:,0,:] = 0

            #pragma unroll
            for (int off = 32; off > 0; off >>= 1) p3 += __shfl_xor(p3, off);

            float surp3 = fast_tanh(k3 * p3);
            float s3p = __expf(a3 * __logf(fmaxf(surp3, 1e-7f)));
            float gate = fmaf(Bg, s3p, Ag);

            #pragma unroll
            for (int j = 0; j < 4; ++j) {
                v4f ov;
                ov.x = g[j].x * gate; ov.y = g[j].y * gate;
                ov.z = g[j].z * gate; ov.w = g[j].w * gate;
                __builtin_nontemporal_store(ov, (v4f*)(orow + 256 * j));
            }
            #pragma unroll
            for (int j = 0; j < 4; ++j) xv[j] = xn[j];
            xr += Dd; orow += Dd;
        }
    }
}

// ----------------------------------------------------------------------------
extern "C" void kernel_launch(void* const* d_in, const int* in_sizes, int n_in,
                              void* d_out, int out_size, void* d_ws, size_t ws_size,
                              hipStream_t stream) {
    const float* x        = (const float*)d_in[0];
    const float* ema_mean = (const float*)d_in[1];
    const float* ema_sq   = (const float*)d_in[2];
    const float* ema_out  = (const float*)d_in[3];
    const float* var_fast = (const float*)d_in[4];
    const float* var_slow = (const float*)d_in[5];
    const float* log_tau  = (const float*)d_in[6];
    const float* log_sig1 = (const float*)d_in[7];
    const float* log_sig2 = (const float*)d_in[8];
    const float* log_sig3 = (const float*)d_in[9];
    const float* log_w    = (const float*)d_in[10];
    const float* log_a1   = (const float*)d_in[11];
    const float* log_a2   = (const float*)d_in[12];
    const float* log_a3   = (const float*)d_in[13];
    float* out = (float*)d_out;

    // ws layout (floats): [0..16) barrier counters, [1024..) segp interleaved
    // (sx,ss): 2*B*NSEG*D floats (~16.8 MB). ws is 512 MiB.
    float* ws   = (float*)d_ws;
    unsigned* bar = (unsigned*)ws;
    float* segp = ws + 1024;

    // zero the two barrier counters (ws is poisoned between iterations)
    hipMemsetAsync(bar, 0, 64, stream);

    fused_all_kernel<<<GRID_BLOCKS, 256, 0, stream>>>(
        x, ema_mean, ema_sq, ema_out, var_fast, var_slow,
        log_tau, log_sig1, log_sig2, log_sig3, log_w, log_a1, log_a2, log_a3,
        bar, segp, out);
}

// Round 5
// 97.425 us; speedup vs baseline: 2.3055x; 2.3055x over previous
//
#include <hip/hip_runtime.h>
#include <math.h>

// Shapes fixed by setup_inputs(): x[8, 4096, 1024] fp32, output same.
#define Bb 8
#define Tt 4096
#define Dd 1024
#define EPSf 1e-5f
#define EPSVARf 1e-4f
#define NSEG 512          // segments per (b) along T
#define NSEG_LOG2 9
#define SEGT (Tt / NSEG)  // 8 rows per segment

typedef float v4f __attribute__((ext_vector_type(4)));

// tanh(y) = 1 - 2/(exp(2y)+1); saturates correctly for |y| large
__device__ __forceinline__ float fast_tanh(float y) {
    float e = __expf(2.0f * y);
    return fmaf(-2.0f, __builtin_amdgcn_rcpf(e + 1.0f), 1.0f);
}

__device__ __forceinline__ float softplus_f(float v) { return log1pf(expf(v)); }

// ---------------- pass 1: prep-in-LDS + gates + segment totals ---------------
// Prep folded in via LDS (round-4 Phase A, verified correct; round-1 lesson:
// keeping per-d consts in registers causes remat/VGPR blowup — LDS is clean).
// 2-row-deep prefetch: row i+2's loads issue before row i's compute, so
// ~2x450cyc of compute covers ~900cyc HBM latency (round-4 lesson: these
// kernels are latency-bound, not BW-bound; traffic was already minimal).
__global__ __launch_bounds__(256, 3) void pass1_kernel(
    const float* __restrict__ x,
    const float* __restrict__ ema_mean, const float* __restrict__ ema_sq,
    const float* __restrict__ ema_out,
    const float* __restrict__ var_fast, const float* __restrict__ var_slow,
    const float* __restrict__ p_log_tau, const float* __restrict__ p_log_sig1,
    const float* __restrict__ p_log_sig2, const float* __restrict__ p_log_w,
    const float* __restrict__ p_log_a1, const float* __restrict__ p_log_a2,
    float* __restrict__ rowc, float* __restrict__ segp)
{
    __shared__ float s_iv[Dd], s_cc[Dd], s_eo[Dd];
    __shared__ float s_red[8];

    int tid = threadIdx.x;
    int lane = tid & 63;
    int wv = tid >> 6;
    int d0 = lane * 4;

    int gw = blockIdx.x * 4 + wv;
    int b = gw >> NSEG_LOG2, seg = gw & (NSEG - 1);
    int t0 = seg * SEGT;
    const float* xr = x + ((size_t)b * Tt + t0) * Dd + d0;
    float* rc = rowc + ((size_t)b * Tt + t0) * 2;

    // issue first two rows' loads immediately (overlap with prep math)
    float4 xv[4], xn[4];
    #pragma unroll
    for (int j = 0; j < 4; ++j) xv[j] = *(const float4*)(xr + 256 * j);
    #pragma unroll
    for (int j = 0; j < 4; ++j) xn[j] = *(const float4*)(xr + Dd + 256 * j);

    // ---- prep: per-d constants into LDS + block reductions ----
    float brs = 0.f, ses = 0.f;
    {
        int dd = tid * 4;
        float4 m4 = *(const float4*)(ema_mean + dd);
        float4 q4 = *(const float4*)(ema_sq + dd);
        float4 e4 = *(const float4*)(ema_out + dd);
        float4 vf = *(const float4*)(var_fast + dd);
        float4 vs = *(const float4*)(var_slow + dd);
        float4 ivv, ccv;
#define PREP(C) { \
        float m = m4.C; \
        float vg = fmaxf(q4.C - m * m, EPSVARf); \
        float ivd = 1.0f / (sqrtf(vg) + EPSf); \
        ivv.C = ivd; ccv.C = m * ivd; \
        brs += fminf(vf.C / fmaxf(vs.C, EPSVARf), 10.0f); \
        ses = fmaf(e4.C, e4.C, ses); }
        PREP(x) PREP(y) PREP(z) PREP(w)
#undef PREP
        *(float4*)(s_iv + dd) = ivv;
        *(float4*)(s_cc + dd) = ccv;
        *(float4*)(s_eo + dd) = e4;
    }
    #pragma unroll
    for (int off = 32; off > 0; off >>= 1) {
        brs += __shfl_xor(brs, off);
        ses += __shfl_xor(ses, off);
    }
    if (lane == 0) { s_red[wv] = brs; s_red[4 + wv] = ses; }
    __syncthreads();
    brs = s_red[0] + s_red[1] + s_red[2] + s_red[3];
    ses = s_red[4] + s_red[5] + s_red[6] + s_red[7];

    // scalar params (redundant per thread; broadcast loads)
    float tau  = expf(p_log_tau[0]);
    float k1   = softplus_f(p_log_sig1[0]) * (1.0f / (float)Dd);
    float sig2 = softplus_f(p_log_sig2[0]);
    float w    = softplus_f(p_log_w[0]);
    float a1   = softplus_f(p_log_a1[0]);
    float a2   = softplus_f(p_log_a2[0]);
    float burst = fmaxf(brs * (1.0f / (float)Dd) - 1.0f, 0.0f);
    float surp2 = tanhf(sig2 * burst);
    float s2p   = expf(a2 * logf(fmaxf(surp2, 1e-7f)));
    float inv_en = 1.0f / fmaxf(sqrtf(ses), 1e-12f);

    float4 rsx[4] = {{0,0,0,0},{0,0,0,0},{0,0,0,0},{0,0,0,0}};
    float4 rss[4] = {{0,0,0,0},{0,0,0,0},{0,0,0,0},{0,0,0,0}};

    #pragma unroll 1
    for (int i = 0; i < SEGT; ++i) {
        float4 xn2[4];
        if (i + 2 < SEGT) {
            #pragma unroll
            for (int j = 0; j < 4; ++j) xn2[j] = *(const float4*)(xr + 2 * Dd + 256 * j);
        }
        float p1 = 0.f, pg2 = 0.f, pge = 0.f;

#define COMP(J, C) { \
        float xvv = xv[J].C; \
        p1 += fabsf(fmaf(xvv, ivj.C, -ccj.C)); \
        float xx = xvv * xvv; \
        float u2 = xvv * fmaf(0.07135481628f, xx, 1.59576912161f); \
        float e  = __expf(u2); \
        float th = fmaf(-2.0f, __builtin_amdgcn_rcpf(e + 1.0f), 1.0f); \
        float hx = 0.5f * xvv; \
        float gg = fmaf(hx, th, hx); \
        pg2 = fmaf(gg, gg, pg2); \
        pge = fmaf(gg, eoj.C, pge); \
        rsx[J].C += xvv; \
        rss[J].C = fmaf(xvv, xvv, rss[J].C); \
    }
        #pragma unroll
        for (int j = 0; j < 4; ++j) {
            float4 ivj = *(const float4*)(s_iv + d0 + 256 * j);
            float4 ccj = *(const float4*)(s_cc + d0 + 256 * j);
            float4 eoj = *(const float4*)(s_eo + d0 + 256 * j);
            COMP(j, x) COMP(j, y) COMP(j, z) COMP(j, w)
        }
#undef COMP

        #pragma unroll
        for (int off = 32; off > 0; off >>= 1) {
            p1  += __shfl_xor(p1,  off);
            pg2 += __shfl_xor(pg2, off);
            pge += __shfl_xor(pge, off);
        }
        // per-row gate constants (all lanes compute; lane 0 stores)
        float surp1 = fast_tanh(k1 * p1);
        float s1p = __expf(a1 * __logf(fmaxf(surp1, 1e-7f)));
        float rg = __builtin_amdgcn_rsqf(fmaxf(pg2, 1e-24f));
        float cs = fminf(fmaxf(pge * rg * inv_en, -1.0f), 1.0f);
        float A = __expf(-tau * cs);
        float Bv = A * w * s1p * s2p;
        if (lane == 0) { float2 ab; ab.x = A; ab.y = Bv; *(float2*)rc = ab; }

        #pragma unroll
        for (int j = 0; j < 4; ++j) { xv[j] = xn[j]; xn[j] = xn2[j]; }
        xr += Dd; rc += 2;
    }

    // interleaved segment totals: (sx,ss) pairs, 32 B contiguous per lane
    float* sp = segp + ((size_t)(b * NSEG + seg) * Dd + d0) * 2;
    #pragma unroll
    for (int j = 0; j < 4; ++j) {
        float4 lo, hi;
        lo.x = rsx[j].x; lo.y = rss[j].x; lo.z = rsx[j].y; lo.w = rss[j].y;
        hi.x = rsx[j].z; hi.y = rss[j].z; hi.z = rsx[j].w; hi.w = rss[j].w;
        *(float4*)(sp + 512 * j) = lo;
        *(float4*)(sp + 512 * j + 4) = hi;
    }
}

// ---------------- pass 2: parallel exclusive scan over segments --------------
// 16 sub-scanners per (b,d) column on interleaved float2 (sx,ss) pairs.
__global__ __launch_bounds__(512) void seg_scan_kernel(float2* __restrict__ segp)
{
    constexpr int K = 16;
    constexpr int COLS = 32;
    constexpr int CH = NSEG / K;       // 32
    int tid = threadIdx.x;
    int col = tid & (COLS - 1);
    int q = tid >> 5;
    int gcol = blockIdx.x * COLS + col;   // 0 .. B*D-1
    int b = gcol >> 10, d = gcol & 1023;
    float2* p = segp + ((size_t)b * NSEG + (size_t)q * CH) * Dd + d;

    // phase 1: sub-chain totals
    float ax = 0.f, as = 0.f;
    #pragma unroll 4
    for (int s = 0; s < CH; ++s) {
        float2 v = p[(size_t)s * Dd];
        ax += v.x; as += v.y;
    }
    __shared__ float lx[K][COLS], ls[K][COLS];
    lx[q][col] = ax; ls[q][col] = as;
    __syncthreads();
    float rx = 0.f, rs = 0.f;
    for (int r = 0; r < q; ++r) { rx += lx[r][col]; rs += ls[r][col]; }

    // phase 2: exclusive write with running prefix
    for (int s = 0; s < CH; ++s) {
        size_t o = (size_t)s * Dd;
        float2 v = p[o];
        float2 e; e.x = rx; e.y = rs;
        p[o] = e;
        rx += v.x; rs += v.y;
    }
}

// ---------------- pass 3: signal-3 + gelu + gate + write ---------------------
// 2-row-deep prefetch; gelu written in place into xv (saves 16 VGPRs so the
// deeper pipeline fits under the (256,3) cap); NT out-stores keep x L3-hot.
__global__ __launch_bounds__(256, 3) void fused_main_kernel(
    const float* __restrict__ x,
    const float* __restrict__ p_log_sig3, const float* __restrict__ p_log_a3,
    const float* __restrict__ rowc, const float* __restrict__ segp,
    float* __restrict__ out)
{
    int gw = (blockIdx.x * 256 + threadIdx.x) >> 6;
    int lane = threadIdx.x & 63;
    int b = gw >> NSEG_LOG2, seg = gw & (NSEG - 1);
    int d0 = lane * 4;

    int t0 = seg * SEGT;
    const float* xr = x + ((size_t)b * Tt + t0) * Dd + d0;
    const float* rc = rowc + ((size_t)b * Tt + t0) * 2;
    float* orow = out + ((size_t)b * Tt + t0) * Dd + d0;

    float4 xv[4], xn[4];
    #pragma unroll
    for (int j = 0; j < 4; ++j) xv[j] = *(const float4*)(xr + 256 * j);
    #pragma unroll
    for (int j = 0; j < 4; ++j) xn[j] = *(const float4*)(xr + Dd + 256 * j);

    float4 rsx[4], rss[4];
    const float* sp = segp + ((size_t)(b * NSEG + seg) * Dd + d0) * 2;
    #pragma unroll
    for (int j = 0; j < 4; ++j) {
        float4 lo = *(const float4*)(sp + 512 * j);
        float4 hi = *(const float4*)(sp + 512 * j + 4);
        rsx[j].x = lo.x; rss[j].x = lo.y; rsx[j].y = lo.z; rss[j].y = lo.w;
        rsx[j].z = hi.x; rss[j].z = hi.y; rsx[j].w = hi.z; rss[j].w = hi.w;
    }
    float k3 = softplus_f(p_log_sig3[0]) * (1.0f / (float)Dd);
    float a3 = softplus_f(p_log_a3[0]);

    #pragma unroll 1
    for (int i = 0; i < SEGT; ++i) {
        int t = t0 + i;
        float4 xn2[4];
        if (i + 2 < SEGT) {
            #pragma unroll
            for (int j = 0; j < 4; ++j) xn2[j] = *(const float4*)(xr + 2 * Dd + 256 * j);
        }
        float2 ab = *(const float2*)rc;   // wave-uniform broadcast load

        float p3 = 0.f;
        float invt = (t > 0) ? __builtin_amdgcn_rcpf((float)t) : 0.0f;

        // NOTE: gelu result overwrites xv[J].C (in-place) — xv not needed after
#define COMP(J, C) { \
        float xvv = xv[J].C; \
        float mu = rsx[J].C * invt; \
        float vr = fmaxf(fmaf(-mu, mu, rss[J].C * invt), EPSVARf); \
        float rq = __builtin_amdgcn_rsqf(vr); \
        float ri = rq * fmaf(-EPSf, rq, 1.0f); \
        p3 += fabsf((xvv - mu) * ri); \
        rsx[J].C += xvv; \
        rss[J].C = fmaf(xvv, xvv, rss[J].C); \
        float xx = xvv * xvv; \
        float u2 = xvv * fmaf(0.07135481628f, xx, 1.59576912161f); \
        float e  = __expf(u2); \
        float th = fmaf(-2.0f, __builtin_amdgcn_rcpf(e + 1.0f), 1.0f); \
        float hx = 0.5f * xvv; \
        xv[J].C = fmaf(hx, th, hx); \
    }
        #pragma unroll
        for (int j = 0; j < 4; ++j) { COMP(j, x) COMP(j, y) COMP(j, z) COMP(j, w) }
#undef COMP
        if (t == 0) p3 = 0.f;   // reference forces z3[:,0,:] = 0

        #pragma unroll
        for (int off = 32; off > 0; off >>= 1) p3 += __shfl_xor(p3, off);

        float surp3 = fast_tanh(k3 * p3);
        float s3p = __expf(a3 * __logf(fmaxf(surp3, 1e-7f)));
        float gate = fmaf(ab.y, s3p, ab.x);

        #pragma unroll
        for (int j = 0; j < 4; ++j) {
            v4f ov;
            ov.x = xv[j].x * gate; ov.y = xv[j].y * gate;
            ov.z = xv[j].z * gate; ov.w = xv[j].w * gate;
            __builtin_nontemporal_store(ov, (v4f*)(orow + 256 * j));
        }
        #pragma unroll
        for (int j = 0; j < 4; ++j) { xv[j] = xn[j]; xn[j] = xn2[j]; }
        xr += Dd; rc += 2; orow += Dd;
    }
}

// ----------------------------------------------------------------------------
extern "C" void kernel_launch(void* const* d_in, const int* in_sizes, int n_in,
                              void* d_out, int out_size, void* d_ws, size_t ws_size,
                              hipStream_t stream) {
    const float* x        = (const float*)d_in[0];
    const float* ema_mean = (const float*)d_in[1];
    const float* ema_sq   = (const float*)d_in[2];
    const float* ema_out  = (const float*)d_in[3];
    const float* var_fast = (const float*)d_in[4];
    const float* var_slow = (const float*)d_in[5];
    const float* log_tau  = (const float*)d_in[6];
    const float* log_sig1 = (const float*)d_in[7];
    const float* log_sig2 = (const float*)d_in[8];
    const float* log_sig3 = (const float*)d_in[9];
    const float* log_w    = (const float*)d_in[10];
    const float* log_a1   = (const float*)d_in[11];
    const float* log_a2   = (const float*)d_in[12];
    const float* log_a3   = (const float*)d_in[13];
    float* out = (float*)d_out;

    // ws layout (floats): rowc (A,B per row) = 2*B*T, then segp interleaved
    // (sx,ss): 2*B*NSEG*D floats (~33.5 MB). ws is 512 MiB.
    float* ws   = (float*)d_ws;
    float* rowc = ws;
    float* segp = rowc + 2 * (size_t)Bb * Tt;

    pass1_kernel<<<Bb * NSEG / 4, 256, 0, stream>>>(
        x, ema_mean, ema_sq, ema_out, var_fast, var_slow,
        log_tau, log_sig1, log_sig2, log_w, log_a1, log_a2,
        rowc, segp);

    seg_scan_kernel<<<Bb * Dd / 32, 512, 0, stream>>>((float2*)segp);

    fused_main_kernel<<<Bb * NSEG / 4, 256, 0, stream>>>(
        x, log_sig3, log_a3, rowc, segp, out);
}